// Round 5
// baseline (546.060 us; speedup 1.0000x reference)
//
#include <hip/hip_runtime.h>

// CombinedLoss: 0.7*MSE + 0.3*mean_b softDTW_gamma.  B=64, T=1024, C=8, fp32.
// One block (16 waves) per batch, wave w owns rows [64w,64w+63].
// R5: register-streamed t-columns. Per diagonal:
//  - fresh column t(k-base) read as wave-uniform BROADCAST (prefetched),
//    flows lane-to-lane via DPP wave_shr:1  (kills R4's 2304 B/diag LDS reads)
//  - halo from upstream wave staged ONCE per 16-diag window into lanes 0..15,
//    rotated into lane 0 by DPP wave_shl:1 (only DPP old-lane0 is consumed)
//  - softmin via min3/med3/max3: exp of the min is 1 -> only 2 exp + 1 log
//  - scalar (readfirstlane) window bounds -> inactive waves branch away

constexpr int BB = 64;
constexpr int TT = 1024;
constexpr int CC = 8;
constexpr float ALPHA_ = 0.7f;
constexpr float GAMMA_ = 0.2f;
constexpr float FINF = 1000000000.0f;
constexpr int DB = 16;
constexpr int NSTEP = 143;     // 2047/16 + 15 skew
constexpr int NCOL = 1092;     // 1024 + pad (prefetch reaches j0=1088)

// lane l <- v from lane l-1; lane 0 <- old0[lane0]   (v_mov_b32 dpp wave_shr:1)
__device__ __forceinline__ float shflup1(float old0, float v) {
    return __int_as_float(__builtin_amdgcn_update_dpp(
        __float_as_int(old0), __float_as_int(v), 0x138, 0xf, 0xf, false));
}
// lane l <- v from lane l+1 (wave_shl:1); lane 63 <- 0
__device__ __forceinline__ float shfldn1(float v) {
    return __int_as_float(__builtin_amdgcn_update_dpp(
        0, __float_as_int(v), 0x130, 0xf, 0xf, false));
}

__global__ __launch_bounds__(1024) void sdtw_kernel(
    const float* __restrict__ pred, const float* __restrict__ target,
    float* __restrict__ ws)
{
    __shared__ float4 s_p4[NCOL * 2];   // [-2t0..3],[-2t4..7] per column
    __shared__ float  s_y2[NCOL];
    __shared__ float  s_halo[16][64];   // per-wave bottom-row ring
    __shared__ float  s_red[16];

    const int b = blockIdx.x;
    const int i = threadIdx.x;                                // row
    const int l = i & 63;
    const int wid  = __builtin_amdgcn_readfirstlane(i >> 6);  // scalar
    const int base = wid << 6;

    const float* pr = pred   + ((size_t)b * TT + i) * CC;
    const float* tr = target + ((size_t)b * TT + i) * CC;
    const float4 pa = ((const float4*)pr)[0];
    const float4 pb = ((const float4*)pr)[1];
    const float4 ta = ((const float4*)tr)[0];
    const float4 tb = ((const float4*)tr)[1];

    float x2 = 0.f, y2 = 0.f, msep = 0.f;
    {
        const float tt[CC] = {ta.x,ta.y,ta.z,ta.w,tb.x,tb.y,tb.z,tb.w};
        const float pp[CC] = {pa.x,pa.y,pa.z,pa.w,pb.x,pb.y,pb.z,pb.w};
        #pragma unroll
        for (int c = 0; c < CC; ++c) {
            x2 = fmaf(pp[c], pp[c], x2);
            y2 = fmaf(tt[c], tt[c], y2);
            float d = pp[c] - tt[c];
            msep = fmaf(d, d, msep);
        }
    }
    s_p4[2*i]   = make_float4(-2.f*ta.x, -2.f*ta.y, -2.f*ta.z, -2.f*ta.w);
    s_p4[2*i+1] = make_float4(-2.f*tb.x, -2.f*tb.y, -2.f*tb.z, -2.f*tb.w);
    s_y2[i] = y2;
    if (i < NCOL - TT) {                     // zero pad columns
        s_p4[2*(TT+i)]   = make_float4(0.f,0.f,0.f,0.f);
        s_p4[2*(TT+i)+1] = make_float4(0.f,0.f,0.f,0.f);
        s_y2[TT+i] = 0.f;
    }

    // fused MSE partial
    #pragma unroll
    for (int off = 32; off > 0; off >>= 1)
        msep += __shfl_down(msep, off, 64);
    if (l == 0) s_red[wid] = msep;
    __syncthreads();
    if (i == 0) {
        float s = 0.f;
        #pragma unroll
        for (int q = 0; q < 16; ++q) s += s_red[q];
        ws[b] = s;
    }

    const float c1 = 7.21347520444482f;   // log2(e)/gamma
    const float c2 = 0.13862943611199f;   // gamma*ln(2)
    float r1 = FINF, r2 = FINF;           // r_{k-1}(i), r_{k-2}(i)
    float tf0=0,tf1=0,tf2=0,tf3=0,tf4=0,tf5=0,tf6=0,tf7=0, y2f=0;
    int   j = -i;                          // j = k - i, maintained incrementally
    const int lastk = base + 63 + TT - 1;

    for (int s = 0; s < NSTEP; ++s) {
        const int k0 = DB * (s - wid);               // scalar window base
        if (k0 >= base && k0 <= lastk) {             // active (always full start)
            int khi = k0 + DB - 1;
            if (khi > lastk) khi = lastk;
            const int nd = khi - k0;                 // scalar, 15 except tail

            // stage halo: lane l holds halo[k0-1+l]; rotate into lane0 per diag
            float hv, hvd;
            if (wid == 0) {
                hv  = FINF;
                hvd = (k0 == 0 && l == 0) ? 0.0f : FINF;
            } else {
                hv  = s_halo[wid-1][(k0 - 1 + l) & 63];
                hvd = s_halo[wid-1][(k0 - 2 + l) & 63];
            }
            // stage first column (wave-uniform broadcast read)
            int j0 = k0 - base;
            float4 A  = s_p4[2*j0];
            float4 Bq = s_p4[2*j0+1];
            float  y2n = s_y2[j0];
            j = k0 - i;

            #define DIAG_BODY(K)                                              \
            {                                                                 \
                tf0 = shflup1(A.x,  tf0); tf1 = shflup1(A.y,  tf1);           \
                tf2 = shflup1(A.z,  tf2); tf3 = shflup1(A.w,  tf3);           \
                tf4 = shflup1(Bq.x, tf4); tf5 = shflup1(Bq.y, tf5);           \
                tf6 = shflup1(Bq.z, tf6); tf7 = shflup1(Bq.w, tf7);           \
                y2f = shflup1(y2n,  y2f);                                     \
                const float up   = shflup1(hv,  r1);                          \
                const float dg   = shflup1(hvd, r2);                          \
                const float left = r1;                                        \
                hv  = shfldn1(hv);                                            \
                hvd = shfldn1(hvd);                                           \
                ++j0;                                                         \
                A = s_p4[2*j0]; Bq = s_p4[2*j0+1]; y2n = s_y2[j0];            \
                float acc = x2 + y2f;                                         \
                acc = fmaf(pa.x, tf0, acc); acc = fmaf(pa.y, tf1, acc);       \
                acc = fmaf(pa.z, tf2, acc); acc = fmaf(pa.w, tf3, acc);       \
                acc = fmaf(pb.x, tf4, acc); acc = fmaf(pb.y, tf5, acc);       \
                acc = fmaf(pb.z, tf6, acc); acc = fmaf(pb.w, tf7, acc);       \
                const float m  = fminf(fminf(up, left), dg);                  \
                const float M  = fmaxf(fmaxf(up, left), dg);                  \
                const float md = __builtin_amdgcn_fmed3f(up, left, dg);       \
                const float mc = m * c1;                                      \
                const float e1 = __builtin_amdgcn_exp2f(fmaf(md, -c1, mc));   \
                const float e2 = __builtin_amdgcn_exp2f(fmaf(M,  -c1, mc));   \
                const float lg = __builtin_amdgcn_logf(1.0f + (e1 + e2));     \
                float rn = acc + fmaf(-c2, lg, m);                            \
                rn = ((unsigned)j < (unsigned)TT) ? rn : FINF;                \
                ++j;                                                          \
                r2 = r1; r1 = rn;                                             \
                if (l == 63) s_halo[wid][(K) & 63] = rn;                      \
            }

            if (nd == DB - 1) {                      // full window, unrolled
                #pragma unroll
                for (int d = 0; d < DB; ++d) DIAG_BODY(k0 + d)
            } else {                                 // tail window
                for (int k = k0; k <= khi; ++k) DIAG_BODY(k)
            }
            #undef DIAG_BODY
        }
        __syncthreads();
    }
    if (i == TT - 1) ws[BB + b] = r1;                // r_{2T-2}(T-1)
}

__global__ __launch_bounds__(64) void finalize_kernel(
    const float* __restrict__ ws, float* __restrict__ out)
{
    int t = threadIdx.x;
    float mse = ws[t];
    float sd  = ws[BB + t];
    #pragma unroll
    for (int off = 32; off > 0; off >>= 1) {
        mse += __shfl_down(mse, off, 64);
        sd  += __shfl_down(sd,  off, 64);
    }
    if (t == 0) {
        float msev = mse / (float)((size_t)BB * TT * CC);
        float sdtw = sd  / (float)BB;
        out[0] = ALPHA_ * msev + (1.0f - ALPHA_) * sdtw;
    }
}

extern "C" void kernel_launch(void* const* d_in, const int* in_sizes, int n_in,
                              void* d_out, int out_size, void* d_ws, size_t ws_size,
                              hipStream_t stream) {
    const float* pred   = (const float*)d_in[0];
    const float* target = (const float*)d_in[1];
    float* ws  = (float*)d_ws;
    float* out = (float*)d_out;

    sdtw_kernel<<<BB, TT, 0, stream>>>(pred, target, ws);
    finalize_kernel<<<1, 64, 0, stream>>>(ws, out);
}